// Round 1
// baseline (2474.027 us; speedup 1.0000x reference)
//
#include <hip/hip_runtime.h>

// ---------------------------------------------------------------------------
// StyleDecorator: whiten(content), whiten(style) via Newton-Schulz inverse
// sqrt of 512x512 covariances; patch match via S0 cross-Gram + 9-tap diagonal
// stencil; gather/overlap-add; color via NS sqrt. All fp32.
// ---------------------------------------------------------------------------

#define CH    512
#define NPIX  4096      // 64*64
#define WD    64
#define HPAD  66
#define PPAD  4356      // 66*66
#define LPAD  68        // LDS leading-dim pad (float4-aligned, conflict-free)
#define NS_ITERS 14

// ---------------- fp32 64x64 tile core: 16x16 threads, 4x4 each -------------
__device__ __forceinline__ void core16(const float (*As)[LPAD], const float (*Bs)[LPAD],
                                       float acc[4][4], int tx, int ty) {
#pragma unroll
  for (int kk = 0; kk < 16; ++kk) {
    const float4 av = *(const float4*)(&As[kk][ty * 4]);
    const float4 bv = *(const float4*)(&Bs[kk][tx * 4]);
    const float a[4] = {av.x, av.y, av.z, av.w};
    const float b[4] = {bv.x, bv.y, bv.z, bv.w};
#pragma unroll
    for (int i = 0; i < 4; ++i)
#pragma unroll
      for (int j = 0; j < 4; ++j)
        acc[i][j] = fmaf(a[i], b[j], acc[i][j]);
  }
}

// ---------------- per-(matrix,channel) mean over 4096 pixels ----------------
__global__ __launch_bounds__(256)
void mean_kernel(const float* __restrict__ content, const float* __restrict__ style,
                 float* __restrict__ meanv) {
  int m = blockIdx.x;            // 0..2047 ; matrix z = m>>9, channel c = m&511
  int z = m >> 9, c = m & 511;
  const float* X = ((z < 2) ? content + (size_t)z * CH * NPIX
                            : style   + (size_t)(z - 2) * CH * NPIX) + (size_t)c * NPIX;
  float s = 0.f;
  for (int i = threadIdx.x; i < NPIX; i += 256) s += X[i];
  __shared__ float red[256];
  red[threadIdx.x] = s; __syncthreads();
  for (int w = 128; w > 0; w >>= 1) {
    if (threadIdx.x < w) red[threadIdx.x] += red[threadIdx.x + w];
    __syncthreads();
  }
  if (threadIdx.x == 0) meanv[m] = red[0] * (1.0f / NPIX);
}

// ---------------- cov[z] = (X-mu)(X-mu)^T / 4095,  512x512, K=4096 ----------
__global__ __launch_bounds__(256)
void cov_kernel(const float* __restrict__ content, const float* __restrict__ style,
                const float* __restrict__ meanv, float* __restrict__ cov) {
  int z = blockIdx.z;
  const float* X  = (z < 2) ? content + (size_t)z * CH * NPIX
                            : style   + (size_t)(z - 2) * CH * NPIX;
  const float* mu = meanv + z * CH;
  float* C = cov + (size_t)z * CH * CH;
  int gm0 = blockIdx.y * 64, gn0 = blockIdx.x * 64;
  int tid = threadIdx.x, tx = tid & 15, ty = tid >> 4;
  int lk = tid & 15, lm = tid >> 4;
  __shared__ float As[16][LPAD], Bs[16][LPAD];
  float acc[4][4] = {};
  for (int k0 = 0; k0 < NPIX; k0 += 16) {
#pragma unroll
    for (int i = 0; i < 4; ++i) {
      int m = lm + i * 16;
      As[lk][m] = X[(size_t)(gm0 + m) * NPIX + k0 + lk] - mu[gm0 + m];
      Bs[lk][m] = X[(size_t)(gn0 + m) * NPIX + k0 + lk] - mu[gn0 + m];
    }
    __syncthreads();
    core16(As, Bs, acc, tx, ty);
    __syncthreads();
  }
  const float s = 1.0f / 4095.0f;
#pragma unroll
  for (int i = 0; i < 4; ++i)
#pragma unroll
    for (int j = 0; j < 4; ++j)
      C[(size_t)(gm0 + ty * 4 + i) * CH + gn0 + tx * 4 + j] = acc[i][j] * s;
}

// ---------------- scale[z] = {c, 1/c, sqrt(c), rsqrt(c)}, c = ||A||_inf -----
__global__ __launch_bounds__(256)
void scale_kernel(const float* __restrict__ cov, float* __restrict__ scales) {
  int z = blockIdx.x;
  const float* C = cov + (size_t)z * CH * CH;
  float mx = 0.f;
  for (int r = threadIdx.x; r < CH; r += 256) {
    float s = 0.f;
    for (int c2 = 0; c2 < CH; ++c2) s += fabsf(C[(size_t)r * CH + c2]);
    mx = fmaxf(mx, s);
  }
  __shared__ float red[256];
  red[threadIdx.x] = mx; __syncthreads();
  for (int w = 128; w > 0; w >>= 1) {
    if (threadIdx.x < w) red[threadIdx.x] = fmaxf(red[threadIdx.x], red[threadIdx.x + w]);
    __syncthreads();
  }
  if (threadIdx.x == 0) {
    float c = red[0];
    scales[z * 4 + 0] = c;
    scales[z * 4 + 1] = 1.0f / c;
    scales[z * 4 + 2] = sqrtf(c);
    scales[z * 4 + 3] = rsqrtf(c);
  }
}

// ---------------- Y = cov/c, Z = I ------------------------------------------
__global__ __launch_bounds__(256)
void ns_init_kernel(const float* __restrict__ cov, const float* __restrict__ scales,
                    float* __restrict__ Y, float* __restrict__ Z) {
  size_t t = (size_t)blockIdx.x * 256 + threadIdx.x;   // 4*512*512 total
  int z = (int)(t >> 18);
  size_t e = t & 262143;
  int row = (int)(e >> 9), col = (int)(e & 511);
  Y[t] = cov[t] * scales[z * 4 + 1];
  Z[t] = (row == col) ? 1.0f : 0.0f;
}

// ---------------- T = 1.5 I - 0.5 * (Z*Y)  (batched z=4, 512^3) -------------
__global__ __launch_bounds__(256)
void ns_t_kernel(const float* __restrict__ Zb, const float* __restrict__ Yb,
                 float* __restrict__ Tb) {
  int z = blockIdx.z;
  const float* A = Zb + (size_t)z * CH * CH;   // row-major M x K
  const float* B = Yb + (size_t)z * CH * CH;   // row-major K x N
  float* C = Tb + (size_t)z * CH * CH;
  int gm0 = blockIdx.y * 64, gn0 = blockIdx.x * 64;
  int tid = threadIdx.x, tx = tid & 15, ty = tid >> 4;
  int lk = tid & 15, lm = tid >> 4;
  int ln = tid & 63, lk4 = tid >> 6;
  __shared__ float As[16][LPAD], Bs[16][LPAD];
  float acc[4][4] = {};
  for (int k0 = 0; k0 < CH; k0 += 16) {
#pragma unroll
    for (int i = 0; i < 4; ++i) {
      int m = lm + i * 16;
      As[lk][m] = A[(size_t)(gm0 + m) * CH + k0 + lk];
      int k = lk4 * 4 + i;
      Bs[k][ln] = B[(size_t)(k0 + k) * CH + gn0 + ln];
    }
    __syncthreads();
    core16(As, Bs, acc, tx, ty);
    __syncthreads();
  }
#pragma unroll
  for (int i = 0; i < 4; ++i)
#pragma unroll
    for (int j = 0; j < 4; ++j) {
      int gm = gm0 + ty * 4 + i, gn = gn0 + tx * 4 + j;
      C[(size_t)gm * CH + gn] = -0.5f * acc[i][j] + ((gm == gn) ? 1.5f : 0.0f);
    }
}

// ---------------- Yn = Y*T (z<4) ; Zn = T*Z (z>=4)  (batched z=8) -----------
__global__ __launch_bounds__(256)
void ns_upd_kernel(const float* __restrict__ Yb, const float* __restrict__ Zb,
                   const float* __restrict__ Tb, float* __restrict__ Ynb,
                   float* __restrict__ Znb) {
  int z = blockIdx.z;
  int m4 = z & 3;
  bool first = (z < 4);
  const float* A = (first ? Yb : Tb) + (size_t)m4 * CH * CH;
  const float* B = (first ? Tb : Zb) + (size_t)m4 * CH * CH;
  float* C = (first ? Ynb : Znb) + (size_t)m4 * CH * CH;
  int gm0 = blockIdx.y * 64, gn0 = blockIdx.x * 64;
  int tid = threadIdx.x, tx = tid & 15, ty = tid >> 4;
  int lk = tid & 15, lm = tid >> 4;
  int ln = tid & 63, lk4 = tid >> 6;
  __shared__ float As[16][LPAD], Bs[16][LPAD];
  float acc[4][4] = {};
  for (int k0 = 0; k0 < CH; k0 += 16) {
#pragma unroll
    for (int i = 0; i < 4; ++i) {
      int m = lm + i * 16;
      As[lk][m] = A[(size_t)(gm0 + m) * CH + k0 + lk];
      int k = lk4 * 4 + i;
      Bs[k][ln] = B[(size_t)(k0 + k) * CH + gn0 + ln];
    }
    __syncthreads();
    core16(As, Bs, acc, tx, ty);
    __syncthreads();
  }
#pragma unroll
  for (int i = 0; i < 4; ++i)
#pragma unroll
    for (int j = 0; j < 4; ++j)
      C[(size_t)(gm0 + ty * 4 + i) * CH + gn0 + tx * 4 + j] = acc[i][j];
}

// ---------------- whitened = (Z * rsqrt(c)) * (X - mu), into padded 66x66 ---
__global__ __launch_bounds__(256)
void whiten_apply_kernel(const float* __restrict__ content, const float* __restrict__ style,
                         const float* __restrict__ Zb, const float* __restrict__ meanv,
                         const float* __restrict__ scales,
                         float* __restrict__ ncp, float* __restrict__ nsp) {
  int z = blockIdx.z;                        // 0,1 content ; 2,3 style
  const float* A  = Zb + (size_t)z * CH * CH;
  const float* X  = (z < 2) ? content + (size_t)z * CH * NPIX
                            : style   + (size_t)(z - 2) * CH * NPIX;
  const float* mu = meanv + z * CH;
  float* out = (z < 2) ? ncp + (size_t)z * CH * PPAD
                       : nsp + (size_t)(z - 2) * CH * PPAD;
  float alpha = scales[z * 4 + 3];
  int gm0 = blockIdx.y * 64, gn0 = blockIdx.x * 64;
  int tid = threadIdx.x, tx = tid & 15, ty = tid >> 4;
  int lk = tid & 15, lm = tid >> 4;
  int ln = tid & 63, lk4 = tid >> 6;
  __shared__ float As[16][LPAD], Bs[16][LPAD];
  float acc[4][4] = {};
  for (int k0 = 0; k0 < CH; k0 += 16) {
#pragma unroll
    for (int i = 0; i < 4; ++i) {
      int m = lm + i * 16;
      As[lk][m] = A[(size_t)(gm0 + m) * CH + k0 + lk];
      int k = lk4 * 4 + i;
      Bs[k][ln] = X[(size_t)(k0 + k) * NPIX + gn0 + ln] - mu[k0 + k];
    }
    __syncthreads();
    core16(As, Bs, acc, tx, ty);
    __syncthreads();
  }
#pragma unroll
  for (int i = 0; i < 4; ++i) {
    int c = gm0 + ty * 4 + i;
#pragma unroll
    for (int j = 0; j < 4; ++j) {
      int n = gn0 + tx * 4 + j;
      int y = n >> 6, x = n & 63;
      out[(size_t)c * PPAD + (size_t)(y + 1) * HPAD + (x + 1)] = acc[i][j] * alpha;
    }
  }
}

// ---------------- column norms^2 of padded whitened style -------------------
__global__ __launch_bounds__(256)
void cn2_kernel(const float* __restrict__ nsp, float* __restrict__ cn2) {
  int b = blockIdx.y;
  int p = blockIdx.x * 256 + threadIdx.x;
  if (p >= PPAD) return;
  const float* base = nsp + (size_t)b * CH * PPAD + p;
  float s = 0.f;
  for (int c = 0; c < CH; ++c) { float v = base[(size_t)c * PPAD]; s = fmaf(v, v, s); }
  cn2[(size_t)b * PPAD + p] = s;
}

// ---------------- rnorm[p] = 1/(sqrt(sum of 9 taps)+1e-5) -------------------
__global__ __launch_bounds__(256)
void rnorm_kernel(const float* __restrict__ cn2, float* __restrict__ rnorm) {
  int b = blockIdx.y;
  int p = blockIdx.x * 256 + threadIdx.x;   // 0..4095
  int py = p >> 6, px = p & 63;
  const float* c2 = cn2 + (size_t)b * PPAD + (size_t)py * HPAD + px;
  float s = 0.f;
#pragma unroll
  for (int i = 0; i < 3; ++i)
#pragma unroll
    for (int j = 0; j < 3; ++j) s += c2[i * HPAD + j];
  rnorm[b * 4096 + p] = 1.0f / (sqrtf(s) + 1e-5f);
}

// ---------------- S0T[p'][q'] = sum_c nsp[c][p'] * ncp[c][q'] ---------------
__global__ __launch_bounds__(256)
void s0_kernel(const float* __restrict__ Anp, const float* __restrict__ Bnp,
               float* __restrict__ S0T) {
  int gm0 = blockIdx.y * 64, gn0 = blockIdx.x * 64;
  int tid = threadIdx.x, tx = tid & 15, ty = tid >> 4;
  int lm = tid & 63, lk4 = tid >> 6;
  __shared__ float As[16][LPAD], Bs[16][LPAD];
  float acc[4][4] = {};
  int mA = gm0 + lm; bool okA = mA < PPAD;
  int nB = gn0 + lm; bool okB = nB < PPAD;
  for (int k0 = 0; k0 < CH; k0 += 16) {
#pragma unroll
    for (int i = 0; i < 4; ++i) {
      int k = lk4 * 4 + i;
      As[k][lm] = okA ? Anp[(size_t)(k0 + k) * PPAD + mA] : 0.0f;
      Bs[k][lm] = okB ? Bnp[(size_t)(k0 + k) * PPAD + nB] : 0.0f;
    }
    __syncthreads();
    core16(As, Bs, acc, tx, ty);
    __syncthreads();
  }
#pragma unroll
  for (int i = 0; i < 4; ++i) {
    int m = gm0 + ty * 4 + i;
    if (m >= PPAD) continue;
#pragma unroll
    for (int j = 0; j < 4; ++j) {
      int n = gn0 + tx * 4 + j;
      if (n < PPAD) S0T[(size_t)m * PPAD + n] = acc[i][j];
    }
  }
}

// ---------------- per-p-chunk argmax of 9-tap stencil score -----------------
__global__ __launch_bounds__(256)
void score_partial_kernel(const float* __restrict__ S0T, const float* __restrict__ rnorm,
                          float* __restrict__ pmax, int* __restrict__ pidx, int b) {
  int q = blockIdx.y * 256 + threadIdx.x;
  int chunk = blockIdx.x;
  int qy = q >> 6, qx = q & 63;
  int q0 = qy * HPAD + qx;
  const float* rn = rnorm + b * 4096;
  float best = -1e30f; int bestp = 0;
  for (int p = chunk * 64; p < chunk * 64 + 64; ++p) {
    int py = p >> 6, px = p & 63;
    size_t base = (size_t)(py * HPAD + px) * PPAD + q0;
    float s = 0.f;
#pragma unroll
    for (int i = 0; i < 3; ++i)
#pragma unroll
      for (int j = 0; j < 3; ++j) {
        int d = i * HPAD + j;
        s += S0T[base + (size_t)d * (PPAD + 1)];
      }
    s *= rn[p];
    if (s > best) { best = s; bestp = p; }
  }
  pmax[(size_t)chunk * 4096 + q] = best;
  pidx[(size_t)chunk * 4096 + q] = bestp;
}

__global__ __launch_bounds__(256)
void argmax_merge_kernel(const float* __restrict__ pmax, const int* __restrict__ pidx,
                         int* __restrict__ idx, int b) {
  int q = blockIdx.x * 256 + threadIdx.x;
  float best = -1e30f; int bp = 0;
  for (int ch = 0; ch < 64; ++ch) {
    float v = pmax[(size_t)ch * 4096 + q];
    if (v > best) { best = v; bp = pidx[(size_t)ch * 4096 + q]; }
  }
  idx[b * 4096 + q] = bp;
}

// ---------------- gather matched patches, overlap-add, normalize ------------
__global__ __launch_bounds__(256)
void gather_kernel(const float* __restrict__ nsp, const int* __restrict__ idx,
                   float* __restrict__ R) {
  size_t t = (size_t)blockIdx.x * 256 + threadIdx.x;  // 2*512*4096
  int r = (int)(t & 4095);
  int c = (int)((t >> 12) & 511);
  int b = (int)(t >> 21);
  int y = r >> 6, x = r & 63;
  const float* nspb = nsp + (size_t)b * CH * PPAD + (size_t)c * PPAD;
  const int* idxb = idx + b * 4096;
  float s = 0.f; int cnt = 0;
#pragma unroll
  for (int i = 0; i < 3; ++i) {
    int qy = y + 1 - i;
    if ((unsigned)qy >= 64u) continue;
#pragma unroll
    for (int j = 0; j < 3; ++j) {
      int qx = x + 1 - j;
      if ((unsigned)qx >= 64u) continue;
      int p = idxb[qy * 64 + qx];
      int py = p >> 6, px = p & 63;
      s += nspb[(size_t)(py + i) * HPAD + (px + j)];
      cnt++;
    }
  }
  R[t] = s / (float)cnt;
}

// ---------------- out = (Y*sqrt(c)) * R + style_mean ------------------------
__global__ __launch_bounds__(256)
void color_kernel(const float* __restrict__ Yb, const float* __restrict__ R,
                  const float* __restrict__ meanv, const float* __restrict__ scales,
                  float* __restrict__ O) {
  int b = blockIdx.z;
  const float* A  = Yb + (size_t)(2 + b) * CH * CH;
  const float* B  = R + (size_t)b * CH * NPIX;
  const float* mu = meanv + (2 + b) * CH;
  float alpha = scales[(2 + b) * 4 + 2];
  float* out = O + (size_t)b * CH * NPIX;
  int gm0 = blockIdx.y * 64, gn0 = blockIdx.x * 64;
  int tid = threadIdx.x, tx = tid & 15, ty = tid >> 4;
  int lk = tid & 15, lm = tid >> 4;
  int ln = tid & 63, lk4 = tid >> 6;
  __shared__ float As[16][LPAD], Bs[16][LPAD];
  float acc[4][4] = {};
  for (int k0 = 0; k0 < CH; k0 += 16) {
#pragma unroll
    for (int i = 0; i < 4; ++i) {
      int m = lm + i * 16;
      As[lk][m] = A[(size_t)(gm0 + m) * CH + k0 + lk];
      int k = lk4 * 4 + i;
      Bs[k][ln] = B[(size_t)(k0 + k) * NPIX + gn0 + ln];
    }
    __syncthreads();
    core16(As, Bs, acc, tx, ty);
    __syncthreads();
  }
#pragma unroll
  for (int i = 0; i < 4; ++i) {
    int m = gm0 + ty * 4 + i;
    float mum = mu[m];
#pragma unroll
    for (int j = 0; j < 4; ++j)
      out[(size_t)m * NPIX + gn0 + tx * 4 + j] = acc[i][j] * alpha + mum;
  }
}

// ---------------------------------------------------------------------------
extern "C" void kernel_launch(void* const* d_in, const int* in_sizes, int n_in,
                              void* d_out, int out_size, void* d_ws, size_t ws_size,
                              hipStream_t stream) {
  (void)in_sizes; (void)n_in; (void)out_size; (void)ws_size;
  const float* content = (const float*)d_in[0];
  const float* style   = (const float*)d_in[1];
  float* out = (float*)d_out;

  // workspace layout (~154 MB total)
  char* base = (char*)d_ws;
  size_t off = 0;
  auto take = [&](size_t nbytes) -> char* {
    char* p = base + off;
    off = (off + nbytes + 255) & ~(size_t)255;
    return p;
  };
  float* meanv  = (float*)take((size_t)4 * CH * sizeof(float));
  float* scales = (float*)take(16 * sizeof(float));
  float* cov    = (float*)take((size_t)4 * CH * CH * sizeof(float));
  float* Ybuf   = (float*)take((size_t)4 * CH * CH * sizeof(float));
  float* Zbuf   = (float*)take((size_t)4 * CH * CH * sizeof(float));
  float* Ynb    = (float*)take((size_t)4 * CH * CH * sizeof(float));
  float* Znb    = (float*)take((size_t)4 * CH * CH * sizeof(float));
  float* Tb     = (float*)take((size_t)4 * CH * CH * sizeof(float));
  float* ncp    = (float*)take((size_t)2 * CH * PPAD * sizeof(float));
  float* nsp    = (float*)take((size_t)2 * CH * PPAD * sizeof(float));
  float* cn2    = (float*)take((size_t)2 * PPAD * sizeof(float));
  float* rnormb = (float*)take((size_t)2 * 4096 * sizeof(float));
  float* S0T    = (float*)take((size_t)PPAD * PPAD * sizeof(float));
  float* pmax   = (float*)take((size_t)64 * 4096 * sizeof(float));
  int*   pidx   = (int*)  take((size_t)64 * 4096 * sizeof(int));
  int*   idxb   = (int*)  take((size_t)2 * 4096 * sizeof(int));
  float* R      = (float*)take((size_t)2 * CH * NPIX * sizeof(float));

  // zero the padded whitened buffers (borders must be 0; ws is poisoned)
  hipMemsetAsync(ncp, 0, (size_t)2 * CH * PPAD * sizeof(float), stream);
  hipMemsetAsync(nsp, 0, (size_t)2 * CH * PPAD * sizeof(float), stream);

  mean_kernel<<<2048, 256, 0, stream>>>(content, style, meanv);
  cov_kernel<<<dim3(8, 8, 4), 256, 0, stream>>>(content, style, meanv, cov);
  scale_kernel<<<4, 256, 0, stream>>>(cov, scales);
  ns_init_kernel<<<4096, 256, 0, stream>>>(cov, scales, Ybuf, Zbuf);

  float *Yc = Ybuf, *Zc = Zbuf, *Yn = Ynb, *Zn = Znb;
  for (int it = 0; it < NS_ITERS; ++it) {
    ns_t_kernel<<<dim3(8, 8, 4), 256, 0, stream>>>(Zc, Yc, Tb);
    ns_upd_kernel<<<dim3(8, 8, 8), 256, 0, stream>>>(Yc, Zc, Tb, Yn, Zn);
    float* t1 = Yc; Yc = Yn; Yn = t1;
    float* t2 = Zc; Zc = Zn; Zn = t2;
  }

  whiten_apply_kernel<<<dim3(64, 8, 4), 256, 0, stream>>>(content, style, Zc, meanv,
                                                          scales, ncp, nsp);
  cn2_kernel<<<dim3(18, 2), 256, 0, stream>>>(nsp, cn2);
  rnorm_kernel<<<dim3(16, 2), 256, 0, stream>>>(cn2, rnormb);

  for (int b = 0; b < 2; ++b) {
    s0_kernel<<<dim3(69, 69), 256, 0, stream>>>(nsp + (size_t)b * CH * PPAD,
                                                ncp + (size_t)b * CH * PPAD, S0T);
    score_partial_kernel<<<dim3(64, 16), 256, 0, stream>>>(S0T, rnormb, pmax, pidx, b);
    argmax_merge_kernel<<<16, 256, 0, stream>>>(pmax, pidx, idxb, b);
  }

  gather_kernel<<<16384, 256, 0, stream>>>(nsp, idxb, R);
  color_kernel<<<dim3(64, 8, 2), 256, 0, stream>>>(Yc, R, meanv, scales, out);
}

// Round 2
// 1482.612 us; speedup vs baseline: 1.6687x; 1.6687x over previous
//
#include <hip/hip_runtime.h>

// ---------------------------------------------------------------------------
// StyleDecorator, round 2: every GEMM on MFMA via bf16x3 split (6-term,
// fp32-equivalent precision ~2^-24 so the patch argmax can't flip).
// All GEMM operands stored as [out-dim][K] bf16 rows (hi/mid/lo). NS matrices
// are symmetric (polynomials of cov) so no transposes needed there.
// ---------------------------------------------------------------------------

#define CH    512
#define NPIX  4096      // 64*64
#define HPAD  66
#define PPAD  4356      // 66*66
#define MROWS 4480      // padded row count for whitened-feature matrices
#define BANDW 2304      // S0T column band width (two bands cover 4416 cols)
#define BANDOFF 2112    // second band column offset
#define NS_ITERS 11

typedef unsigned short u16;
typedef __attribute__((ext_vector_type(8))) short short8;   // 8 bf16 (4 VGPRs)
typedef __attribute__((ext_vector_type(4))) float f32x4;    // MFMA C/D

__device__ __forceinline__ u16 bf16_rn(float x){
  union { float f; unsigned u; } v; v.f = x;
  unsigned u = v.u;
  return (u16)((u + 0x7FFFu + ((u >> 16) & 1u)) >> 16);
}
__device__ __forceinline__ float bf2f(u16 h){
  union { unsigned u; float f; } v; v.u = ((unsigned)h) << 16;
  return v.f;
}
__device__ __forceinline__ void split3(float x, u16& h, u16& m, u16& l){
  h = bf16_rn(x);
  float r1 = x - bf2f(h);
  m = bf16_rn(r1);
  l = bf16_rn(r1 - bf2f(m));
}
__device__ __forceinline__ void gll16(const void* g, void* l){
  __builtin_amdgcn_global_load_lds((const __attribute__((address_space(1))) unsigned*)g,
                                   (__attribute__((address_space(3))) unsigned*)l,
                                   16, 0, 0);
}
__device__ __forceinline__ f32x4 mfma_bf16(short8 a, short8 b, f32x4 c){
  return __builtin_amdgcn_mfma_f32_16x16x32_bf16(a, b, c, 0, 0, 0);
}

// ---------------------------------------------------------------------------
enum { M_COV = 0, M_NST = 1, M_X3 = 2, M_WHITEN = 3, M_S0 = 4, M_COLOR = 5 };

struct GP {
  const u16 *Ah, *Am, *Al, *Bh, *Bm, *Bl;
  size_t sAz, sBz;           // per-z strides (elements)
  float* Cf;
  u16 *Ch, *Cm, *Cl;
  size_t sCz;
  const float* scales;
  const float* meanv;
  int K;
};

// C[m][n] = sum_k A[m][k]*B[n][k] with A,B stored as [row][K] bf16x3.
// 256 threads = 4 waves; TILE in {64,128}; wave computes (TILE/2)^2.
template<int TILE, int MODE>
__global__ __launch_bounds__(256, 2)
void gemm_sp(GP p){
  constexpr int MF = TILE / 32;
  const int z = blockIdx.z;
  const u16* __restrict__ Ah = p.Ah + (size_t)z * p.sAz;
  const u16* __restrict__ Am = p.Am + (size_t)z * p.sAz;
  const u16* __restrict__ Al = p.Al + (size_t)z * p.sAz;
  const u16* __restrict__ Bh = p.Bh + (size_t)z * p.sBz;
  const u16* __restrict__ Bm = p.Bm + (size_t)z * p.sBz;
  const u16* __restrict__ Bl = p.Bl + (size_t)z * p.sBz;
  const int m0 = blockIdx.y * TILE, n0 = blockIdx.x * TILE;
  const int tid = threadIdx.x, ln = tid & 63, wv = tid >> 6;
  const int wm = (wv >> 1) * (TILE/2), wn = (wv & 1) * (TILE/2);
  __shared__ __align__(16) u16 sAh[TILE*32], sAm[TILE*32], sAl[TILE*32];
  __shared__ __align__(16) u16 sBh[TILE*32], sBm[TILE*32], sBl[TILE*32];
  f32x4 acc[MF][MF];
#pragma unroll
  for(int i=0;i<MF;++i)
#pragma unroll
    for(int j=0;j<MF;++j) acc[i][j] = (f32x4)0.0f;
  const int K = p.K;
  for(int k0 = 0; k0 < K; k0 += 32){
#pragma unroll
    for(int s = tid; s < TILE*4; s += 256){      // 16B slots, 4 per row
      const int row = s >> 2, sub = s & 3;
      const size_t ga = (size_t)(m0 + row) * K + k0 + sub*8;
      const size_t gb = (size_t)(n0 + row) * K + k0 + sub*8;
      gll16(Ah + ga, sAh + s*8);
      gll16(Am + ga, sAm + s*8);
      gll16(Al + ga, sAl + s*8);
      gll16(Bh + gb, sBh + s*8);
      gll16(Bm + gb, sBm + s*8);
      gll16(Bl + gb, sBl + s*8);
    }
    __syncthreads();
    short8 ah[MF], am[MF], al[MF], bh[MF], bm[MF], bl[MF];
#pragma unroll
    for(int i=0;i<MF;++i){
      const int ofa = (wm + i*16 + (ln & 15))*32 + (ln >> 4)*8;
      const int ofb = (wn + i*16 + (ln & 15))*32 + (ln >> 4)*8;
      ah[i] = *(const short8*)(sAh + ofa);
      am[i] = *(const short8*)(sAm + ofa);
      al[i] = *(const short8*)(sAl + ofa);
      bh[i] = *(const short8*)(sBh + ofb);
      bm[i] = *(const short8*)(sBm + ofb);
      bl[i] = *(const short8*)(sBl + ofb);
    }
#pragma unroll
    for(int i=0;i<MF;++i)
#pragma unroll
      for(int j=0;j<MF;++j){
        acc[i][j] = mfma_bf16(ah[i], bh[j], acc[i][j]);
        acc[i][j] = mfma_bf16(ah[i], bm[j], acc[i][j]);
        acc[i][j] = mfma_bf16(am[i], bh[j], acc[i][j]);
        acc[i][j] = mfma_bf16(am[i], bm[j], acc[i][j]);
        acc[i][j] = mfma_bf16(ah[i], bl[j], acc[i][j]);
        acc[i][j] = mfma_bf16(al[i], bh[j], acc[i][j]);
      }
    __syncthreads();
  }
  // epilogue: C/D layout col=lane&15, row=(lane>>4)*4+reg
#pragma unroll
  for(int i=0;i<MF;++i)
#pragma unroll
    for(int j=0;j<MF;++j)
#pragma unroll
      for(int r=0;r<4;++r){
        const int m = m0 + wm + i*16 + (ln >> 4)*4 + r;
        const int n = n0 + wn + j*16 + (ln & 15);
        float v = acc[i][j][r];
        if constexpr (MODE == M_COV){
          p.Cf[(size_t)z * p.sCz + (size_t)m * CH + n] = v * (1.0f/4095.0f);
        } else if constexpr (MODE == M_NST){
          v = -0.5f*v + ((m == n) ? 1.5f : 0.0f);
          u16 h, mm2, l; split3(v, h, mm2, l);
          const size_t o = (size_t)z*p.sCz + (size_t)m*CH + n;
          p.Ch[o] = h; p.Cm[o] = mm2; p.Cl[o] = l;
        } else if constexpr (MODE == M_X3){
          u16 h, mm2, l; split3(v, h, mm2, l);
          const size_t o = (size_t)z*p.sCz + (size_t)m*CH + n;
          p.Ch[o] = h; p.Cm[o] = mm2; p.Cl[o] = l;
        } else if constexpr (MODE == M_WHITEN){
          v *= p.scales[z*4 + 3];                 // rsqrt(c)
          const int prow = ((m >> 6) + 1)*HPAD + (m & 63) + 1;
          u16 h, mm2, l; split3(v, h, mm2, l);
          const size_t o = (size_t)z*p.sCz + (size_t)prow*CH + n;
          p.Ch[o] = h; p.Cm[o] = mm2; p.Cl[o] = l;
        } else if constexpr (MODE == M_S0){
          p.Cf[(size_t)m * BANDW + n] = v;
        } else {                                  // M_COLOR
          const float sc = p.scales[(2+z)*4 + 2]; // sqrt(c)
          const float mu = p.meanv[(2+z)*CH + m];
          p.Cf[(size_t)z*p.sCz + (size_t)m*NPIX + n] = v*sc + mu;
        }
      }
}

// ---------------- per-(matrix,channel) mean over 4096 pixels ----------------
__global__ __launch_bounds__(256)
void mean_kernel(const float* __restrict__ content, const float* __restrict__ style,
                 float* __restrict__ meanv){
  int mm = blockIdx.x;           // 0..2047
  int z = mm >> 9, c = mm & 511;
  const float* X = ((z < 2) ? content + (size_t)z * CH * NPIX
                            : style   + (size_t)(z - 2) * CH * NPIX) + (size_t)c * NPIX;
  float s = 0.f;
  for(int i = threadIdx.x; i < NPIX; i += 256) s += X[i];
  __shared__ float red[256];
  red[threadIdx.x] = s; __syncthreads();
  for(int w = 128; w > 0; w >>= 1){
    if(threadIdx.x < w) red[threadIdx.x] += red[threadIdx.x + w];
    __syncthreads();
  }
  if(threadIdx.x == 0) meanv[mm] = red[0] * (1.0f / NPIX);
}

// ------- center + bf16x3 split, emit both [c][pix] and [pix][c] layouts -----
__global__ __launch_bounds__(256)
void center_split_kernel(const float* __restrict__ content, const float* __restrict__ style,
                         const float* __restrict__ meanv,
                         u16* __restrict__ Xch, u16* __restrict__ Xcm, u16* __restrict__ Xcl,
                         u16* __restrict__ XcTh, u16* __restrict__ XcTm, u16* __restrict__ XcTl){
  int z = blockIdx.z;
  const float* X = (z < 2) ? content + (size_t)z * CH * NPIX
                           : style   + (size_t)(z - 2) * CH * NPIX;
  int p0 = blockIdx.x * 64, c0 = blockIdx.y * 64;
  __shared__ float T[64][65];
  int col = threadIdx.x & 63, rq = threadIdx.x >> 6;
#pragma unroll
  for(int i = 0; i < 16; ++i){
    int r = i*4 + rq;
    int c = c0 + r;
    float v = X[(size_t)c * NPIX + p0 + col] - meanv[z*CH + c];
    u16 h, m, l; split3(v, h, m, l);
    size_t o = (size_t)(z*CH + c) * NPIX + p0 + col;
    Xch[o] = h; Xcm[o] = m; Xcl[o] = l;
    T[col][r] = v;
  }
  __syncthreads();
#pragma unroll
  for(int i = 0; i < 16; ++i){
    int r = i*4 + rq;                 // pixel-in-tile
    float v = T[r][col];
    u16 h, m, l; split3(v, h, m, l);
    size_t o = (size_t)(z*NPIX + p0 + r) * CH + c0 + col;
    XcTh[o] = h; XcTm[o] = m; XcTl[o] = l;
  }
}

// ---------------- scale[z] = {c, 1/c, sqrt(c), rsqrt(c)} --------------------
__global__ __launch_bounds__(256)
void scale_kernel(const float* __restrict__ cov, float* __restrict__ scales){
  int z = blockIdx.x;
  const float* C = cov + (size_t)z * CH * CH;
  float mx = 0.f;
  for(int r = threadIdx.x; r < CH; r += 256){
    float s = 0.f;
    for(int c2 = 0; c2 < CH; ++c2) s += fabsf(C[(size_t)r * CH + c2]);
    mx = fmaxf(mx, s);
  }
  __shared__ float red[256];
  red[threadIdx.x] = mx; __syncthreads();
  for(int w = 128; w > 0; w >>= 1){
    if(threadIdx.x < w) red[threadIdx.x] = fmaxf(red[threadIdx.x], red[threadIdx.x + w]);
    __syncthreads();
  }
  if(threadIdx.x == 0){
    float c = red[0];
    scales[z*4+0] = c;
    scales[z*4+1] = 1.0f / c;
    scales[z*4+2] = sqrtf(c);
    scales[z*4+3] = rsqrtf(c);
  }
}

// ---------------- Y0 = cov/c (x3), Z0 = I (x3) ------------------------------
__global__ __launch_bounds__(256)
void ns_init_kernel(const float* __restrict__ cov, const float* __restrict__ scales,
                    u16* Yh, u16* Ym, u16* Yl, u16* Zh, u16* Zm, u16* Zl){
  size_t t = (size_t)blockIdx.x * 256 + threadIdx.x;   // 4*512*512
  int z = (int)(t >> 18);
  size_t e = t & 262143;
  int row = (int)(e >> 9), col = (int)(e & 511);
  float v = cov[t] * scales[z*4+1];
  u16 h, m, l; split3(v, h, m, l);
  Yh[t] = h; Ym[t] = m; Yl[t] = l;
  Zh[t] = (row == col) ? (u16)0x3F80 : (u16)0;
  Zm[t] = 0; Zl[t] = 0;
}

// ---------------- cn2[p'] = ||whitened style column||^2 ---------------------
__global__ __launch_bounds__(256)
void cn2_kernel(const u16* __restrict__ Wh, const u16* __restrict__ Wm,
                const u16* __restrict__ Wl, float* __restrict__ cn2){
  int b = blockIdx.y;
  int row = blockIdx.x * 16 + (threadIdx.x >> 4);
  int t = threadIdx.x & 15;
  float s = 0.f;
  if(row < PPAD){
    size_t base = ((size_t)(2 + b) * MROWS + row) * CH;
    for(int ch = t; ch < 64; ch += 16){
      uint4 hv = *(const uint4*)(Wh + base + ch*8);
      uint4 mv = *(const uint4*)(Wm + base + ch*8);
      uint4 lv = *(const uint4*)(Wl + base + ch*8);
      const unsigned* hw = (const unsigned*)&hv;
      const unsigned* mw = (const unsigned*)&mv;
      const unsigned* lw = (const unsigned*)&lv;
#pragma unroll
      for(int w = 0; w < 4; ++w){
        float v0 = bf2f((u16)(hw[w] & 0xFFFF)) + bf2f((u16)(mw[w] & 0xFFFF)) + bf2f((u16)(lw[w] & 0xFFFF));
        float v1 = bf2f((u16)(hw[w] >> 16))    + bf2f((u16)(mw[w] >> 16))    + bf2f((u16)(lw[w] >> 16));
        s = fmaf(v0, v0, s); s = fmaf(v1, v1, s);
      }
    }
  }
  for(int off = 8; off; off >>= 1) s += __shfl_down(s, off, 16);
  if(t == 0 && row < PPAD) cn2[b*PPAD + row] = s;
}

// ---------------- rnorm[p] = 1/(sqrt(sum of 9 taps)+1e-5) -------------------
__global__ __launch_bounds__(256)
void rnorm_kernel(const float* __restrict__ cn2, float* __restrict__ rnorm){
  int b = blockIdx.y;
  int p = blockIdx.x * 256 + threadIdx.x;   // 0..4095
  int py = p >> 6, px = p & 63;
  const float* c2 = cn2 + (size_t)b * PPAD + (size_t)py * HPAD + px;
  float s = 0.f;
#pragma unroll
  for(int i = 0; i < 3; ++i)
#pragma unroll
    for(int j = 0; j < 3; ++j) s += c2[i * HPAD + j];
  rnorm[b * 4096 + p] = 1.0f / (sqrtf(s) + 1e-5f);
}

// ---------------- per-p-chunk argmax of 9-tap stencil score (banded) --------
__global__ __launch_bounds__(256)
void score_partial_kernel(const float* __restrict__ S0T, const float* __restrict__ rnorm,
                          float* __restrict__ pmax, int* __restrict__ pidx,
                          int b, int qy0, int colbase){
  int q = qy0*64 + blockIdx.y * 256 + threadIdx.x;
  int chunk = blockIdx.x;
  int qy = q >> 6, qx = q & 63;
  int qcol = qy * HPAD + qx - colbase;
  const float* rn = rnorm + b * 4096;
  float best = -1e30f; int bestp = 0;
  for(int p = chunk * 64; p < chunk * 64 + 64; ++p){
    int py = p >> 6, px = p & 63;
    const float* base = S0T + (size_t)(py * HPAD + px) * BANDW + qcol;
    float s = 0.f;
#pragma unroll
    for(int i = 0; i < 3; ++i)
#pragma unroll
      for(int j = 0; j < 3; ++j)
        s += base[(size_t)(i * HPAD + j) * (BANDW + 1)];
    s *= rn[p];
    if(s > best){ best = s; bestp = p; }
  }
  pmax[(size_t)chunk * 4096 + q] = best;
  pidx[(size_t)chunk * 4096 + q] = bestp;
}

__global__ __launch_bounds__(256)
void argmax_merge_kernel(const float* __restrict__ pmax, const int* __restrict__ pidx,
                         int* __restrict__ idx, int b){
  int q = blockIdx.x * 256 + threadIdx.x;
  float best = -1e30f; int bp = 0;
  for(int ch = 0; ch < 64; ++ch){
    float v = pmax[(size_t)ch * 4096 + q];
    if(v > best){ best = v; bp = pidx[(size_t)ch * 4096 + q]; }
  }
  idx[b * 4096 + q] = bp;
}

// ---------------- gather matched patches, overlap-add, write RT x3 ----------
__global__ __launch_bounds__(256)
void gather_kernel(const u16* __restrict__ Wh, const u16* __restrict__ Wm,
                   const u16* __restrict__ Wl, const int* __restrict__ idx,
                   u16* __restrict__ RTh, u16* __restrict__ RTm, u16* __restrict__ RTl){
  int g = blockIdx.x * 256 + threadIdx.x;   // 2*4096*64
  int cg = g & 63;
  int pix = (g >> 6) & 4095;
  int b = g >> 18;
  int y = pix >> 6, x = pix & 63;
  const int* idxb = idx + b * 4096;
  size_t matbase = (size_t)(2 + b) * MROWS * CH;
  float a8[8] = {0,0,0,0,0,0,0,0};
  int cnt = 0;
#pragma unroll
  for(int i = 0; i < 3; ++i){
    int qy = y + 1 - i;
    if((unsigned)qy >= 64u) continue;
#pragma unroll
    for(int j = 0; j < 3; ++j){
      int qx = x + 1 - j;
      if((unsigned)qx >= 64u) continue;
      int p = idxb[qy * 64 + qx];
      int row = ((p >> 6) + i) * HPAD + (p & 63) + j;
      size_t off = matbase + (size_t)row * CH + cg * 8;
      uint4 hv = *(const uint4*)(Wh + off);
      uint4 mv = *(const uint4*)(Wm + off);
      uint4 lv = *(const uint4*)(Wl + off);
      const unsigned* hw = (const unsigned*)&hv;
      const unsigned* mw = (const unsigned*)&mv;
      const unsigned* lw = (const unsigned*)&lv;
#pragma unroll
      for(int w = 0; w < 4; ++w){
        a8[2*w]   += bf2f((u16)(hw[w] & 0xFFFF)) + bf2f((u16)(mw[w] & 0xFFFF)) + bf2f((u16)(lw[w] & 0xFFFF));
        a8[2*w+1] += bf2f((u16)(hw[w] >> 16))    + bf2f((u16)(mw[w] >> 16))    + bf2f((u16)(lw[w] >> 16));
      }
      ++cnt;
    }
  }
  float inv = 1.0f / (float)cnt;
  u16 oh[8], om[8], ol[8];
#pragma unroll
  for(int k = 0; k < 8; ++k){
    float v = a8[k] * inv;
    split3(v, oh[k], om[k], ol[k]);
  }
  size_t ro = ((size_t)(b * 4096 + pix)) * CH + cg * 8;
  *(uint4*)(RTh + ro) = *(const uint4*)oh;
  *(uint4*)(RTm + ro) = *(const uint4*)om;
  *(uint4*)(RTl + ro) = *(const uint4*)ol;
}

// ---------------------------------------------------------------------------
extern "C" void kernel_launch(void* const* d_in, const int* in_sizes, int n_in,
                              void* d_out, int out_size, void* d_ws, size_t ws_size,
                              hipStream_t stream){
  (void)in_sizes; (void)n_in; (void)out_size; (void)ws_size;
  const float* content = (const float*)d_in[0];
  const float* style   = (const float*)d_in[1];
  float* out = (float*)d_out;

  char* base = (char*)d_ws;
  size_t off = 0;
  auto take = [&](size_t nbytes) -> char* {
    char* p = base + off;
    off = (off + nbytes + 255) & ~(size_t)255;
    return p;
  };
  const size_t MAT = (size_t)CH*CH*2;            // 512x512 bf16 bytes
  const size_t FEAT = (size_t)CH*NPIX*2;         // 512x4096 bf16 bytes (16.78MB)
  const size_t WMAT = (size_t)MROWS*CH*2;        // 4480x512 bf16 bytes (4.59MB)

  float* meanv  = (float*)take((size_t)4*CH*sizeof(float));
  float* scales = (float*)take(256);
  float* cov    = (float*)take((size_t)4*CH*CH*sizeof(float));
  u16 *Yh=(u16*)take(4*MAT), *Ym=(u16*)take(4*MAT), *Yl=(u16*)take(4*MAT);
  u16 *Zh=(u16*)take(4*MAT), *Zm=(u16*)take(4*MAT), *Zl=(u16*)take(4*MAT);
  u16 *Th=(u16*)take(4*MAT), *Tm=(u16*)take(4*MAT), *Tl=(u16*)take(4*MAT);
  u16 *Ynh=(u16*)take(4*MAT), *Ynm=(u16*)take(4*MAT), *Ynl=(u16*)take(4*MAT);
  u16 *Znh=(u16*)take(4*MAT), *Znm=(u16*)take(4*MAT), *Znl=(u16*)take(4*MAT);
  // P1: Xc x3 (center->cov)  then  WT x3 (post-NS -> end)
  char* P1 = take(3*(size_t)4*WMAT);             // 55.05 MB (>= 3*4*FEAT/... )
  u16 *Xch=(u16*)P1, *Xcm=(u16*)(P1+4*FEAT), *Xcl=(u16*)(P1+8*FEAT);
  u16 *Wh=(u16*)P1, *Wm=(u16*)(P1+4*WMAT), *Wl=(u16*)(P1+8*WMAT);
  // P0: XcT x3 (center->whiten), then S0T band (41.3MB), then RT x3 (25.2MB)
  char* P0 = take(3*(size_t)4*FEAT);             // 50.33 MB
  u16 *XcTh=(u16*)P0, *XcTm=(u16*)(P0+4*FEAT), *XcTl=(u16*)(P0+8*FEAT);
  float* S0T = (float*)P0;
  u16 *RTh=(u16*)P0, *RTm=(u16*)(P0+2*FEAT), *RTl=(u16*)(P0+4*FEAT);
  float* cn2    = (float*)take((size_t)2*PPAD*sizeof(float));
  float* rnormb = (float*)take((size_t)2*4096*sizeof(float));
  float* pmax   = (float*)take((size_t)64*4096*sizeof(float));
  int*   pidx   = (int*)  take((size_t)64*4096*sizeof(int));
  int*   idxb   = (int*)  take((size_t)2*4096*sizeof(int));

  mean_kernel<<<2048, 256, 0, stream>>>(content, style, meanv);
  center_split_kernel<<<dim3(64, 8, 4), 256, 0, stream>>>(content, style, meanv,
                                                          Xch, Xcm, Xcl, XcTh, XcTm, XcTl);
  // cov = Xc * Xc^T / 4095
  {
    GP g{}; g.Ah=Xch; g.Am=Xcm; g.Al=Xcl; g.Bh=Xch; g.Bm=Xcm; g.Bl=Xcl;
    g.sAz = g.sBz = (size_t)CH*NPIX; g.Cf = cov; g.sCz = (size_t)CH*CH; g.K = NPIX;
    gemm_sp<64, M_COV><<<dim3(8, 8, 4), 256, 0, stream>>>(g);
  }
  scale_kernel<<<4, 256, 0, stream>>>(cov, scales);
  ns_init_kernel<<<4096, 256, 0, stream>>>(cov, scales, Yh, Ym, Yl, Zh, Zm, Zl);

  u16 *Ach[3]={Yh,Ym,Yl}, *Bch[3]={Zh,Zm,Zl}, *An[3]={Ynh,Ynm,Ynl}, *Bn[3]={Znh,Znm,Znl};
  for(int it = 0; it < NS_ITERS; ++it){
    GP t{}; t.Ah=Bch[0]; t.Am=Bch[1]; t.Al=Bch[2];            // Z
    t.Bh=Ach[0]; t.Bm=Ach[1]; t.Bl=Ach[2];                    // Y (symmetric)
    t.sAz = t.sBz = (size_t)CH*CH; t.Ch=Th; t.Cm=Tm; t.Cl=Tl; t.sCz=(size_t)CH*CH; t.K=CH;
    gemm_sp<64, M_NST><<<dim3(8, 8, 4), 256, 0, stream>>>(t);
    GP u1{}; u1.Ah=Ach[0]; u1.Am=Ach[1]; u1.Al=Ach[2];        // Y
    u1.Bh=Th; u1.Bm=Tm; u1.Bl=Tl;                             // T (symmetric)
    u1.sAz=u1.sBz=(size_t)CH*CH; u1.Ch=An[0]; u1.Cm=An[1]; u1.Cl=An[2]; u1.sCz=(size_t)CH*CH; u1.K=CH;
    gemm_sp<64, M_X3><<<dim3(8, 8, 4), 256, 0, stream>>>(u1);
    GP u2{}; u2.Ah=Th; u2.Am=Tm; u2.Al=Tl;                    // T
    u2.Bh=Bch[0]; u2.Bm=Bch[1]; u2.Bl=Bch[2];                 // Z (symmetric)
    u2.sAz=u2.sBz=(size_t)CH*CH; u2.Ch=Bn[0]; u2.Cm=Bn[1]; u2.Cl=Bn[2]; u2.sCz=(size_t)CH*CH; u2.K=CH;
    gemm_sp<64, M_X3><<<dim3(8, 8, 4), 256, 0, stream>>>(u2);
    for(int c = 0; c < 3; ++c){ u16* tmp=Ach[c]; Ach[c]=An[c]; An[c]=tmp;
                                tmp=Bch[c]; Bch[c]=Bn[c]; Bn[c]=tmp; }
  }

  // WT (padded, zero borders) -- Xc region is dead now; Wh/Wm/Wl alias it
  hipMemsetAsync(Wh, 0, 4*WMAT, stream);
  hipMemsetAsync(Wm, 0, 4*WMAT, stream);
  hipMemsetAsync(Wl, 0, 4*WMAT, stream);
  // WT[pix][c] = XcT * Z  (Z symmetric), scaled by rsqrt(c)
  {
    GP w{}; w.Ah=XcTh; w.Am=XcTm; w.Al=XcTl; w.sAz=(size_t)NPIX*CH;
    w.Bh=Bch[0]; w.Bm=Bch[1]; w.Bl=Bch[2]; w.sBz=(size_t)CH*CH;
    w.Ch=Wh; w.Cm=Wm; w.Cl=Wl; w.sCz=(size_t)MROWS*CH; w.scales=scales; w.K=CH;
    gemm_sp<128, M_WHITEN><<<dim3(4, 32, 4), 256, 0, stream>>>(w);
  }
  cn2_kernel<<<dim3(273, 2), 256, 0, stream>>>(Wh, Wm, Wl, cn2);
  rnorm_kernel<<<dim3(16, 2), 256, 0, stream>>>(cn2, rnormb);

  for(int b = 0; b < 2; ++b){
    for(int band = 0; band < 2; ++band){
      GP s{};
      s.Ah = Wh + (size_t)(2+b)*MROWS*CH; s.Am = Wm + (size_t)(2+b)*MROWS*CH; s.Al = Wl + (size_t)(2+b)*MROWS*CH;
      size_t bo = (size_t)b*MROWS*CH + (size_t)(band ? BANDOFF : 0)*CH;
      s.Bh = Wh + bo; s.Bm = Wm + bo; s.Bl = Wl + bo;
      s.sAz = s.sBz = 0; s.Cf = S0T; s.sCz = 0; s.K = CH;
      gemm_sp<128, M_S0><<<dim3(BANDW/128, MROWS/128, 1), 256, 0, stream>>>(s);
      score_partial_kernel<<<dim3(64, 8), 256, 0, stream>>>(S0T, rnormb, pmax, pidx,
                                                            b, band ? 32 : 0,
                                                            band ? BANDOFF : 0);
    }
    argmax_merge_kernel<<<16, 256, 0, stream>>>(pmax, pidx, idxb, b);
  }

  gather_kernel<<<2048, 256, 0, stream>>>(Wh, Wm, Wl, idxb, RTh, RTm, RTl);
  // out = Ys * R * sqrt(c) + mu   (Ys symmetric)
  {
    GP c{}; c.Ah = Ach[0] + 2*(size_t)CH*CH; c.Am = Ach[1] + 2*(size_t)CH*CH; c.Al = Ach[2] + 2*(size_t)CH*CH;
    c.sAz = (size_t)CH*CH;
    c.Bh = RTh; c.Bm = RTm; c.Bl = RTl; c.sBz = (size_t)NPIX*CH;
    c.Cf = out; c.sCz = (size_t)CH*NPIX; c.scales = scales; c.meanv = meanv; c.K = CH;
    gemm_sp<128, M_COLOR><<<dim3(32, 4, 2), 256, 0, stream>>>(c);
  }
}